// Round 11
// baseline (97.547 us; speedup 1.0000x reference)
//
#include <hip/hip_runtime.h>

// ---------------------------------------------------------------------------
// HouseholdODEFunc: soft-location context + leave-one-out attention + GRU + LN
// N=8192 people, H=128. All heavy matmuls in bf16 MFMA, fp32 accum.
// Attention this round: 3 WGs/CU (48KB LDS: K dbuf + V single; <=170 regs via
// VALU lsum denominator + launch_bounds(256,3)), grid 768 (12 uneven chunks),
// counted vmcnt schedule (never 0 mid-loop).
// ---------------------------------------------------------------------------

typedef __attribute__((ext_vector_type(8)))  short bf16x8;
typedef __attribute__((ext_vector_type(4)))  float f32x4;
typedef __attribute__((ext_vector_type(16))) float f32x16;
typedef __attribute__((ext_vector_type(4)))  unsigned uint4v;

#define N_P   8192
#define H_D   128
#define NCHNK 12               // 8 chunks x 11 tiles + 4 chunks x 10 tiles
#define KVB   64
#define LDE   384              // PH2e row stride: ph(128)|social(128)|spatial(64)|time(32)|pad(32)

#if __has_builtin(__builtin_amdgcn_exp2f)
#define EXP2(x) __builtin_amdgcn_exp2f(x)
#else
#define EXP2(x) exp2f(x)
#endif

__device__ __forceinline__ short f2bf(float f) {   // RNE float->bf16 bits
  unsigned u = __float_as_uint(f);
  u = (u + 0x7fffu + ((u >> 16) & 1u)) >> 16;
  return (short)u;
}
__device__ __forceinline__ float bf2f(short s) {
  return __uint_as_float(((unsigned)(unsigned short)s) << 16);
}

// XOR-swizzled byte offset of a 16B slot in a row-major LDS tile.
__device__ __forceinline__ int swzb(int row, int slot, int nslots) {
  return (row * nslots + (slot ^ (row & ((nslots - 1) & 7)))) << 4;
}

__device__ __forceinline__ unsigned cvtpk(float a, float b) {
  unsigned d;
  asm("v_cvt_pk_bf16_f32 %0, %1, %2" : "=v"(d) : "v"(a), "v"(b));
  return d;
}

__device__ __forceinline__ void swap32(unsigned& a, unsigned& b) {
#if __has_builtin(__builtin_amdgcn_permlane32_swap)
  auto r = __builtin_amdgcn_permlane32_swap(a, b, false, false);
  a = r[0]; b = r[1];
#else
  asm volatile("v_permlane32_swap_b32 %0, %1" : "+v"(a), "+v"(b));
#endif
}

typedef __attribute__((address_space(1))) const void GV;
typedef __attribute__((address_space(3))) void LV;
__device__ __forceinline__ void gld_lds16(const void* g, void* l) {
  __builtin_amdgcn_global_load_lds((GV*)g, (LV*)l, 16, 0, 0);
}

__constant__ const float QSCALE = 0.12751551485988857f; // log2(e)/sqrt(128)
#define LOG2E 1.4426950408889634f

// ---------------------------------------------------------------------------
// init: W1/bias1 pack (512 rows: q,k,v,loc) + W_big/bias_big fold + PH2e prep
// blocks [0,64): pack; [64,576): W_big row per WG; [576,1600): prep
// ---------------------------------------------------------------------------
__global__ __launch_bounds__(256) void init_kernel(
    const float* t, const float* W_time, const float* b_time,
    const float* W_loc, const float* b_loc,
    const float* Wq, const float* bq, const float* Wk, const float* bk,
    const float* Wv, const float* bv,
    const float* W_merge, const float* b_merge,
    const float* W_ih, const float* b_ih,
    const float* W_hh, const float* b_hh,
    const float* ph,
    short* W1, float* bias1, short* W_big, float* bias_big, short* PH2e) {
  const int b = blockIdx.x, tidl = threadIdx.x;
  if (b < 64) {
    int tid = b * 256 + tidl, stride = 64 * 256;
    for (int i = tid; i < 512 * 128; i += stride) {
      int r = i >> 7, k = i & 127;
      float v;
      if (r < 128)      v = Wq[r * 128 + k];
      else if (r < 256) v = Wk[(r - 128) * 128 + k];
      else if (r < 384) v = Wv[(r - 256) * 128 + k];
      else if (r < 484) v = W_loc[(r - 384) * 128 + k];
      else              v = 0.f;
      W1[i] = f2bf(v);
    }
    for (int i = tid; i < 512; i += stride) {
      float v;
      if (i < 128)      v = bq[i];
      else if (i < 256) v = bk[i - 128];
      else if (i < 384) v = bv[i - 256];
      else if (i < 484) v = b_loc[i - 384];
      else              v = 0.f;
      bias1[i] = v;
    }
  } else if (b < 576) {
    __shared__ float rowj[128];
    const int n = b - 64;                       // 0..511
    if (tidl < 128) rowj[tidl] = (n < 384) ? W_ih[n * 224 + tidl] : 0.f;
    __syncthreads();
    {
      float acc = 0.f;
      if (n < 384) {
#pragma unroll 8
        for (int j = 0; j < 128; ++j) acc += rowj[j] * W_merge[j * 256 + tidl];
      }
      if (tidl < 128) {
        if (n < 256)      acc += W_hh[n * 128 + tidl];          // gate sum
        else if (n >= 384) acc = W_hh[(n - 128) * 128 + tidl];   // hn row
      }
      W_big[n * 384 + tidl] = f2bf(acc);
    }
    if (tidl < 128) {
      int k2 = 256 + tidl;
      float v = 0.f;
      if (n < 384) {
        if (k2 < 320)      v = W_ih[n * 224 + 128 + (k2 - 256)];   // spatial
        else if (k2 < 352) v = W_ih[n * 224 + 192 + (k2 - 320)];   // time
      }
      W_big[n * 384 + k2] = f2bf(v);
    }
    if (tidl < 64) {
      float p = rowj[tidl] * b_merge[tidl] + rowj[tidl + 64] * b_merge[tidl + 64];
#pragma unroll
      for (int mk = 1; mk < 64; mk <<= 1) p += __shfl_xor(p, mk);
      if (tidl == 0) {
        float bb;
        if (n < 256)      bb = b_ih[n] + p + b_hh[n];
        else if (n < 384) bb = b_ih[n] + p;
        else              bb = b_hh[n - 128];
        bias_big[n] = bb;
      }
    }
  } else {
    int tid = (b - 576) * 256 + tidl, stride = 1024 * 256;
    for (int i = tid; i < N_P * H_D; i += stride) {
      int r = i >> 7, d = i & 127;
      PH2e[r * LDE + d] = f2bf(ph[i]);
    }
    const float t0 = t[0];
    for (int i = tid; i < N_P * 64; i += stride) {
      int r = i >> 6, j = i & 63;
      float v = (j < 32) ? (t0 * W_time[j] + b_time[j]) : 0.f;
      PH2e[r * LDE + 320 + j] = f2bf(v);
    }
  }
}

// ---------------------------------------------------------------------------
// 64x128-tile MFMA GEMM: C[M,N] = X[M,K](bf16, stride ldx) @ W[N,K]^T + bias
// 4 waves (2x2), each 32x64 (2x4 16x16 frags). 48KB LDS -> ~3 WGs/CU.
// MODE 0: q/k/loc global writes; v-tile (blockIdx.y==2) LDS-transposed -> vT.
// MODE 2: gxs bf16 (stride 512).
// ---------------------------------------------------------------------------
template <int MODE, int K>
__global__ __launch_bounds__(256, 3) void gemm64_kernel(
    const short* __restrict__ X, int ldx, const short* __restrict__ W,
    const float* __restrict__ bias,
    short* out_q, short* out_k, short* out_vT, float* out_loc,
    short* out_gx) {
  __shared__ short Xl[64 * 128];    // 16KB
  __shared__ short Wl[128 * 128];   // 32KB (reused as transpose buffer)
  const int tid = threadIdx.x;
  const int bm = blockIdx.x * 64, bn = blockIdx.y * 128;
  const int l = tid & 63, wid = tid >> 6;
  const int g = l >> 4, c = l & 15;
  const int wr = wid >> 1, wc = wid & 1;
  f32x4 acc[2][4] = {};
  constexpr int KT = K / 128;
#pragma unroll 1
  for (int kt = 0; kt < KT; ++kt) {
    const int k0 = kt * 128;
#pragma unroll
    for (int pass = 0; pass < 4; ++pass) {
      int s = tid + pass * 256;            // 0..1023
      int row = s >> 4, p = s & 15;
      int lsl = p ^ (row & 7);             // pre-swizzled source slot
      gld_lds16(X + (size_t)(bm + row) * ldx + k0 + lsl * 8, (char*)Xl + s * 16);
    }
#pragma unroll
    for (int pass = 0; pass < 8; ++pass) {
      int s = tid + pass * 256;            // 0..2047
      int row = s >> 4, p = s & 15;
      int lsl = p ^ (row & 7);
      gld_lds16(W + (size_t)(bn + row) * K + k0 + lsl * 8, (char*)Wl + s * 16);
    }
    __syncthreads();
#pragma unroll
    for (int kc = 0; kc < 4; ++kc) {
      bf16x8 a[2], bfr[4];
#pragma unroll
      for (int mi = 0; mi < 2; ++mi)
        a[mi] = *(const bf16x8*)((const char*)Xl + swzb(wr * 32 + mi * 16 + c, kc * 4 + g, 16));
#pragma unroll
      for (int ni = 0; ni < 4; ++ni)
        bfr[ni] = *(const bf16x8*)((const char*)Wl + swzb(wc * 64 + ni * 16 + c, kc * 4 + g, 16));
#pragma unroll
      for (int mi = 0; mi < 2; ++mi)
#pragma unroll
        for (int ni = 0; ni < 4; ++ni)
          acc[mi][ni] = __builtin_amdgcn_mfma_f32_16x16x32_bf16(a[mi], bfr[ni], acc[mi][ni], 0, 0, 0);
    }
    if (kt + 1 < KT) __syncthreads();
  }
  if constexpr (MODE == 0) {
    if (blockIdx.y == 2) {
      // ---- v panel: LDS transpose -> vT[d][bm..bm+64), coalesced ----
      __syncthreads();                       // done reading Wl
      short* T = Wl;                         // 64 x 130 (pad 2 -> conflict-free)
#pragma unroll
      for (int mi = 0; mi < 2; ++mi)
#pragma unroll
        for (int ni = 0; ni < 4; ++ni)
#pragma unroll
          for (int r = 0; r < 4; ++r) {
            int rl = wr * 32 + mi * 16 + 4 * g + r;    // 0..63
            int cl = wc * 64 + ni * 16 + c;            // 0..127
            T[rl * 130 + cl] = f2bf(acc[mi][ni][r] + bias[256 + cl]);
          }
      __syncthreads();
#pragma unroll
      for (int pass = 0; pass < 32; ++pass) {
        int d = pass * 4 + (tid >> 6);
        int j = tid & 63;
        out_vT[(size_t)d * N_P + bm + j] = T[j * 130 + d];
      }
    } else {
#pragma unroll
      for (int mi = 0; mi < 2; ++mi)
#pragma unroll
        for (int ni = 0; ni < 4; ++ni)
#pragma unroll
          for (int r = 0; r < 4; ++r) {
            int row = bm + wr * 32 + mi * 16 + 4 * g + r;
            int col = bn + wc * 64 + ni * 16 + c;
            float val = acc[mi][ni][r] + bias[col];
            if (col < 128)      out_q[row * 128 + col] = f2bf(val * QSCALE);
            else if (col < 256) out_k[row * 128 + col - 128] = f2bf(val);
            else if (col >= 384 && col < 484) out_loc[row * 112 + col - 384] = val;
          }
    }
  } else {
#pragma unroll
    for (int mi = 0; mi < 2; ++mi)
#pragma unroll
      for (int ni = 0; ni < 4; ++ni)
#pragma unroll
        for (int r = 0; r < 4; ++r) {
          int row = bm + wr * 32 + mi * 16 + 4 * g + r;
          int col = bn + wc * 64 + ni * 16 + c;
          out_gx[row * 512 + col] = f2bf(acc[mi][ni][r] + bias[col]);
        }
  }
}

// ---------------------------------------------------------------------------
// Flash attention. Grid: 64 q-blocks x 12 uneven kv-chunks = 768 WGs of
// 4 waves -> 3 WGs/CU (48KB LDS, <=170 regs). K double-buffered, V single;
// counted vmcnt schedule; frozen tile-0 max; per-lane VALU denominator.
// ---------------------------------------------------------------------------
__global__ __launch_bounds__(256, 3) void attn_kernel(
    const short* __restrict__ qb, const short* __restrict__ kb,
    const short* __restrict__ vT, short* __restrict__ pacc,
    float* __restrict__ pml) {
  __shared__ short Kl[2][KVB * H_D];     // [64 kv][128 d], 16-slot swizzle, 16KB each
  __shared__ short Vl[H_D * KVB];        // [128 d][64 kv], 8-slot swizzle, 16KB
  const int tid = threadIdx.x;
  const int qbk = blockIdx.x / 12, ch = blockIdx.x % 12;
  const int tile0 = ch * 10 + (ch < 8 ? ch : 8);
  const int nt = (ch < 8) ? 11 : 10;
  const int chbase = tile0 * KVB;
  const int l = tid & 63, wid = tid >> 6;
  const int c32 = l & 31, hi = l >> 5;
  const int qrow0w = qbk * 128 + wid * 32;

  char* ldsK = (char*)&Kl[0][0];
  char* ldsV = (char*)&Vl[0];

  auto stageK = [&](int b, int tt) {
    const int off = (tile0 + tt) * KVB;
#pragma unroll
    for (int j = 0; j < 4; ++j) {
      const int i = tid + j * 256;                    // 0..1023
      const int kr = i >> 4, ks = (i & 15) ^ (kr & 15);   // 16-slot swizzle
      gld_lds16(kb + (size_t)(off + kr) * 128 + ks * 8,
                ldsK + b * 16384 + i * 16);
    }
  };
  auto stageV = [&](int tt) {
    const int off = (tile0 + tt) * KVB;
#pragma unroll
    for (int j = 0; j < 4; ++j) {
      const int i = tid + j * 256;
      const int vr = i >> 3, vs = (i & 7) ^ (vr & 7);
      gld_lds16(vT + (size_t)vr * N_P + off + vs * 8,
                ldsV + i * 16);
    }
  };

  bf16x8 qf[8];
#pragma unroll
  for (int sl = 0; sl < 8; ++sl)
    qf[sl] = *(const bf16x8*)(qb + (size_t)(qrow0w + c32) * 128 + sl * 16 + hi * 8);

  // ---- precomputed swizzled LDS read addresses (lane-constant) ----
  const int c15 = c32 & 15;
  const int kbase0 = c32 * 256;
  int koff[8];
#pragma unroll
  for (int sl = 0; sl < 8; ++sl) koff[sl] = ((2 * sl + hi) ^ c15) << 4;
  const int xh = (c32 >> 1) & 3, x0 = c32 & 1;
  const int xb = (hi ^ x0) << 4;
  int voff[4], vbase[4];
#pragma unroll
  for (int s4 = 0; s4 < 4; ++s4) voff[s4] = (s4 ^ xh) << 5;
#pragma unroll
  for (int db = 0; db < 4; ++db) vbase[db] = (db * 32 + c32) * 128 + xb;

  f32x16 acc[4] = {};
  float m = -1e30f, lsum = 0.f;

  // ---- prologue: K0 -> buf0, V0, K1 -> buf1; drain; barrier ----
  stageK(0, 0);
  stageV(0);
  stageK(1, 1);
  asm volatile("s_waitcnt vmcnt(0)" ::: "memory");
  __builtin_amdgcn_s_barrier();

#pragma unroll 1
  for (int t = 0; t < nt; ++t) {
    const int cur = t & 1;
    // W1: K(t) ready for all waves (V(t), K(t+1) may be in flight)
    if (t + 1 < nt) { asm volatile("s_waitcnt vmcnt(8)" ::: "memory"); }
    else            { asm volatile("s_waitcnt vmcnt(4)" ::: "memory"); }
    __builtin_amdgcn_s_barrier();
    asm volatile("" ::: "memory");

    const int kv0 = chbase + t * KVB;
    const char* Kb = ldsK + cur * 16384;

    // ---- S^T = K @ Q^T ----
    f32x16 s0 = {}, s1 = {};
    __builtin_amdgcn_s_setprio(1);
#pragma unroll
    for (int sl = 0; sl < 8; ++sl) {
      bf16x8 k0 = *(const bf16x8*)(Kb + kbase0 + koff[sl]);
      bf16x8 k1 = *(const bf16x8*)(Kb + kbase0 + 8192 + koff[sl]);
      s0 = __builtin_amdgcn_mfma_f32_32x32x16_bf16(k0, qf[sl], s0, 0, 0, 0);
      s1 = __builtin_amdgcn_mfma_f32_32x32x16_bf16(k1, qf[sl], s1, 0, 0, 0);
    }
    __builtin_amdgcn_s_setprio(0);

    // ---- diagonal mask (wave-uniform branch) ----
    if (qrow0w + 32 > kv0 && qrow0w < kv0 + 64) {
      const int qr = qrow0w + c32;
#pragma unroll
      for (int r = 0; r < 16; ++r) {
        const int rowp = (r & 3) + 8 * (r >> 2) + 4 * hi;
        s0[r] = (kv0 + rowp == qr) ? -1e30f : s0[r];
        s1[r] = (kv0 + 32 + rowp == qr) ? -1e30f : s1[r];
      }
    }

    // ---- tile 0 only: per-q-row max, then freeze m ----
    if (t == 0) {
      f32x16 mx;
#pragma unroll
      for (int r = 0; r < 16; ++r) mx[r] = fmaxf(s0[r], s1[r]);
#pragma unroll
      for (int w2 = 8; w2 >= 1; w2 >>= 1)
#pragma unroll
        for (int r = 0; r < w2; ++r) mx[r] = fmaxf(mx[r], mx[r + w2]);
      m = fmaxf(mx[0], __shfl_xor(mx[0], 32));
    }

    // ---- P = exp2(S - m) ----
#pragma unroll
    for (int r = 0; r < 16; ++r) s0[r] = EXP2(s0[r] - m);
#pragma unroll
    for (int r = 0; r < 16; ++r) s1[r] = EXP2(s1[r] - m);

    // W2: V(t) ready for all waves (K(t+1) may still be in flight)
    if (t + 1 < nt) { asm volatile("s_waitcnt vmcnt(4)" ::: "memory"); }
    else            { asm volatile("s_waitcnt vmcnt(0)" ::: "memory"); }
    __builtin_amdgcn_s_barrier();
    asm volatile("" ::: "memory");

    // ---- O += P @ V ; per-lane denominator on VALU ----
    auto pvslice = [&](const f32x16& ss, int base, int sl4) {
      unsigned dA = cvtpk(ss[base + 0], ss[base + 1]);
      unsigned dB = cvtpk(ss[base + 2], ss[base + 3]);
      unsigned dC = cvtpk(ss[base + 4], ss[base + 5]);
      unsigned dD = cvtpk(ss[base + 6], ss[base + 7]);
      swap32(dA, dC);
      swap32(dB, dD);
      uint4v w = {dA, dB, dC, dD};
      bf16x8 pa = __builtin_bit_cast(bf16x8, w);
#pragma unroll
      for (int db = 0; db < 4; ++db) {
        bf16x8 vfr = *(const bf16x8*)(ldsV + vbase[db] + voff[sl4]);
        acc[db] = __builtin_amdgcn_mfma_f32_32x32x16_bf16(pa, vfr, acc[db], 0, 0, 0);
      }
#pragma unroll
      for (int j = 0; j < 8; ++j) lsum += ss[base + j];
    };
    __builtin_amdgcn_s_setprio(1);
    pvslice(s0, 0, 0);
    pvslice(s0, 8, 1);
    pvslice(s1, 0, 2);
    pvslice(s1, 8, 3);
    __builtin_amdgcn_s_setprio(0);

    // W3: release V (and K[cur]) for overwrite; then stage ahead
    if (t + 1 < nt) {
      __builtin_amdgcn_s_barrier();
      asm volatile("" ::: "memory");
      stageV(t + 1);
      if (t + 2 < nt) stageK(cur, t + 2);
    }
  }

  // ---- write partials (unnormalized acc bf16 + per-row m,l) ----
#pragma unroll
  for (int db = 0; db < 4; ++db)
#pragma unroll
    for (int r = 0; r < 16; ++r) {
      const int qr = qrow0w + (r & 3) + 8 * (r >> 2) + 4 * hi;
      pacc[((size_t)ch * N_P + qr) * 128 + db * 32 + c32] = f2bf(acc[db][r]);
    }
  {
    float lv = lsum + __shfl_xor(lsum, 32);
    if (hi == 0) {
      const int qr = qrow0w + c32;
      pml[((size_t)ch * N_P + qr) * 2]     = m;
      pml[((size_t)ch * N_P + qr) * 2 + 1] = lv;
    }
  }
}

// ---------------------------------------------------------------------------
// fused: blocks [0,4096) combine chunk partials -> PH2e cols 128..255;
// blocks [4096,6144) zone softmax + spatial context -> PH2e cols 256..319
// ---------------------------------------------------------------------------
__global__ __launch_bounds__(256) void combine_spatial_kernel(
    const short* __restrict__ pacc, const float* __restrict__ pml,
    const float* __restrict__ locf, const float* __restrict__ E,
    short* __restrict__ PH2e) {
  const int b = blockIdx.x, tid = threadIdx.x;
  if (b < 4096) {
    int row = b * 2 + (tid >> 7);
    int d = tid & 127;
    float mv[NCHNK], lv[NCHNK], M = -1e30f;
#pragma unroll
    for (int cc = 0; cc < NCHNK; ++cc) {
      mv[cc] = pml[(cc * N_P + row) * 2];
      lv[cc] = pml[(cc * N_P + row) * 2 + 1];
      M = fmaxf(M, mv[cc]);
    }
    float L = 0.f, O = 0.f;
#pragma unroll
    for (int cc = 0; cc < NCHNK; ++cc) {
      float w = EXP2(mv[cc] - M);
      L += lv[cc] * w;
      O += bf2f(pacc[((size_t)cc * N_P + row) * 128 + d]) * w;
    }
    PH2e[row * LDE + 128 + d] = f2bf(O / L);
  } else {
    __shared__ float pl[4][104];
    int wid = tid >> 6, l = tid & 63;
    int row = (b - 4096) * 4 + wid;
    float v0 = locf[row * 112 + l];
    float v1 = (l + 64 < 100) ? locf[row * 112 + 64 + l] : -1e30f;
    float m = fmaxf(v0, v1);
#pragma unroll
    for (int mk = 1; mk < 64; mk <<= 1) m = fmaxf(m, __shfl_xor(m, mk));
    float p0 = EXP2((v0 - m) * LOG2E);
    float p1 = (l + 64 < 100) ? EXP2((v1 - m) * LOG2E) : 0.f;
    float s = p0 + p1;
#pragma unroll
    for (int mk = 1; mk < 64; mk <<= 1) s += __shfl_xor(s, mk);
    float inv = 1.f / s;
    pl[wid][l] = p0 * inv;
    if (l + 64 < 100) pl[wid][64 + l] = p1 * inv;
    float acc = 0.f;
#pragma unroll 4
    for (int z = 0; z < 100; ++z) acc += pl[wid][z] * E[z * 64 + l];
    PH2e[row * LDE + 256 + l] = f2bf(acc);
  }
}

// ---------------------------------------------------------------------------
// GRU gates + d = (1-z)(ng-h) + LayerNorm. One wave per row.
// gxs per row (512): [0,128)=xr+hr, [128,256)=xz+hz, [256,384)=xn, [384,512)=hn
// ---------------------------------------------------------------------------
__global__ __launch_bounds__(256) void final_kernel(const short* __restrict__ gxs,
                                                    const float* __restrict__ ph,
                                                    const float* __restrict__ gamma,
                                                    const float* __restrict__ beta,
                                                    float* __restrict__ out) {
  int tid = threadIdx.x, wid = tid >> 6, l = tid & 63;
  int row = blockIdx.x * 4 + wid;
  float dd[2];
#pragma unroll
  for (int half = 0; half < 2; ++half) {
    int d = l + 64 * half;
    float h  = ph[row * 128 + d];
    float sr = bf2f(gxs[row * 512 + d]);
    float sz = bf2f(gxs[row * 512 + 128 + d]);
    float xn = bf2f(gxs[row * 512 + 256 + d]);
    float hn = bf2f(gxs[row * 512 + 384 + d]);
    float r = 1.f / (1.f + EXP2(-LOG2E * sr));
    float z = 1.f / (1.f + EXP2(-LOG2E * sz));
    float a = xn + r * hn;
    float ng = 1.f - 2.f / (1.f + EXP2(2.f * LOG2E * a));  // tanh(a)
    dd[half] = (1.f - z) * (ng - h);
  }
  float s = dd[0] + dd[1], ss = dd[0] * dd[0] + dd[1] * dd[1];
#pragma unroll
  for (int mk = 1; mk < 64; mk <<= 1) {
    s += __shfl_xor(s, mk);
    ss += __shfl_xor(ss, mk);
  }
  float mu = s * (1.f / 128.f);
  float var = ss * (1.f / 128.f) - mu * mu;
  float rs = rsqrtf(var + 1e-5f);
#pragma unroll
  for (int half = 0; half < 2; ++half) {
    int d = l + 64 * half;
    out[row * 128 + d] = (dd[half] - mu) * rs * gamma[d] + beta[d];
  }
}

// ---------------------------------------------------------------------------
extern "C" void kernel_launch(void* const* d_in, const int* in_sizes, int n_in,
                              void* d_out, int out_size, void* d_ws, size_t ws_size,
                              hipStream_t stream) {
  const float* t       = (const float*)d_in[0];
  const float* ph      = (const float*)d_in[1];
  const float* E       = (const float*)d_in[2];
  const float* W_time  = (const float*)d_in[3];
  const float* b_time  = (const float*)d_in[4];
  const float* W_loc   = (const float*)d_in[5];
  const float* b_loc   = (const float*)d_in[6];
  const float* Wq      = (const float*)d_in[7];
  const float* bq      = (const float*)d_in[8];
  const float* Wk      = (const float*)d_in[9];
  const float* bk      = (const float*)d_in[10];
  const float* Wv      = (const float*)d_in[11];
  const float* bv      = (const float*)d_in[12];
  const float* W_merge = (const float*)d_in[13];
  const float* b_merge = (const float*)d_in[14];
  const float* W_ih    = (const float*)d_in[15];
  const float* b_ih    = (const float*)d_in[16];
  const float* W_hh    = (const float*)d_in[17];
  const float* b_hh    = (const float*)d_in[18];
  const float* gamma   = (const float*)d_in[19];
  const float* beta    = (const float*)d_in[20];
  float* out = (float*)d_out;

  char* w = (char*)d_ws;
  auto alloc = [&](size_t bytes) {
    char* p = w;
    w += (bytes + 255) & ~(size_t)255;
    return p;
  };
  short* W1      = (short*)alloc(512 * 128 * 2);
  float* bias1   = (float*)alloc(512 * 4);
  short* W_big   = (short*)alloc(512 * 384 * 2);
  float* bias_big= (float*)alloc(512 * 4);
  short* PH2e    = (short*)alloc((size_t)N_P * LDE * 2);
  short* qbuf    = (short*)alloc((size_t)N_P * 128 * 2);
  short* kbuf    = (short*)alloc((size_t)N_P * 128 * 2);
  short* vT      = (short*)alloc((size_t)128 * N_P * 2);
  float* locf    = (float*)alloc((size_t)N_P * 112 * 4);
  short* gxs     = (short*)alloc((size_t)N_P * 512 * 2);
  short* pacc    = (short*)alloc((size_t)NCHNK * N_P * 128 * 2);
  float* pml     = (float*)alloc((size_t)NCHNK * N_P * 2 * 4);

  init_kernel<<<1600, 256, 0, stream>>>(t, W_time, b_time, W_loc, b_loc, Wq, bq,
                                        Wk, bk, Wv, bv, W_merge, b_merge,
                                        W_ih, b_ih, W_hh, b_hh, ph,
                                        W1, bias1, W_big, bias_big, PH2e);
  gemm64_kernel<0, 128><<<dim3(128, 4), 256, 0, stream>>>(
      PH2e, LDE, W1, bias1, qbuf, kbuf, vT, locf, nullptr);
  attn_kernel<<<768, 256, 0, stream>>>(qbuf, kbuf, vT, pacc, pml);
  combine_spatial_kernel<<<6144, 256, 0, stream>>>(pacc, pml, locf, E, PH2e);
  gemm64_kernel<2, 384><<<dim3(128, 4), 256, 0, stream>>>(
      PH2e, LDE, W_big, bias_big, nullptr, nullptr, nullptr, nullptr, gxs);
  final_kernel<<<2048, 256, 0, stream>>>(gxs, ph, gamma, beta, out);
}

// Round 12
// 88.909 us; speedup vs baseline: 1.0972x; 1.0972x over previous
//
#include <hip/hip_runtime.h>

// ---------------------------------------------------------------------------
// HouseholdODEFunc: soft-location context + leave-one-out attention + GRU + LN
// N=8192 people, H=128. All heavy matmuls in bf16 MFMA, fp32 accum.
// Attention: round-10 kernel (proven best: 2 WGs/CU, K+V double-buffered,
// one drain+barrier per tile, frozen tile-0 max, ones-column MFMA denom).
// This round: revert R11's 3-WG experiment (V-serialization + partial traffic
// regressed); vectorize final_kernel loads (short2/float2 pairs).
// ---------------------------------------------------------------------------

typedef __attribute__((ext_vector_type(8)))  short bf16x8;
typedef __attribute__((ext_vector_type(4)))  float f32x4;
typedef __attribute__((ext_vector_type(16))) float f32x16;
typedef __attribute__((ext_vector_type(4)))  unsigned uint4v;

#define N_P   8192
#define H_D   128
#define NCHNK 8
#define CHLEN (N_P / NCHNK)    // 1024 kv per chunk
#define KVB   64
#define NTIL  (CHLEN / KVB)    // 16 tiles per chunk
#define LDE   384              // PH2e row stride: ph(128)|social(128)|spatial(64)|time(32)|pad(32)

#if __has_builtin(__builtin_amdgcn_exp2f)
#define EXP2(x) __builtin_amdgcn_exp2f(x)
#else
#define EXP2(x) exp2f(x)
#endif

__device__ __forceinline__ short f2bf(float f) {   // RNE float->bf16 bits
  unsigned u = __float_as_uint(f);
  u = (u + 0x7fffu + ((u >> 16) & 1u)) >> 16;
  return (short)u;
}
__device__ __forceinline__ float bf2f(short s) {
  return __uint_as_float(((unsigned)(unsigned short)s) << 16);
}

// XOR-swizzled byte offset of a 16B slot in a row-major LDS tile.
__device__ __forceinline__ int swzb(int row, int slot, int nslots) {
  return (row * nslots + (slot ^ (row & ((nslots - 1) & 7)))) << 4;
}

__device__ __forceinline__ unsigned cvtpk(float a, float b) {
  unsigned d;
  asm("v_cvt_pk_bf16_f32 %0, %1, %2" : "=v"(d) : "v"(a), "v"(b));
  return d;
}

__device__ __forceinline__ void swap32(unsigned& a, unsigned& b) {
#if __has_builtin(__builtin_amdgcn_permlane32_swap)
  auto r = __builtin_amdgcn_permlane32_swap(a, b, false, false);
  a = r[0]; b = r[1];
#else
  asm volatile("v_permlane32_swap_b32 %0, %1" : "+v"(a), "+v"(b));
#endif
}

typedef __attribute__((address_space(1))) const void GV;
typedef __attribute__((address_space(3))) void LV;
__device__ __forceinline__ void gld_lds16(const void* g, void* l) {
  __builtin_amdgcn_global_load_lds((GV*)g, (LV*)l, 16, 0, 0);
}

__constant__ const float QSCALE = 0.12751551485988857f; // log2(e)/sqrt(128)
#define LOG2E 1.4426950408889634f

// ---------------------------------------------------------------------------
// init: W1/bias1 pack (512 rows: q,k,v,loc) + W_big/bias_big fold + PH2e prep
// blocks [0,64): pack; [64,576): W_big row per WG; [576,1600): prep
// ---------------------------------------------------------------------------
__global__ __launch_bounds__(256) void init_kernel(
    const float* t, const float* W_time, const float* b_time,
    const float* W_loc, const float* b_loc,
    const float* Wq, const float* bq, const float* Wk, const float* bk,
    const float* Wv, const float* bv,
    const float* W_merge, const float* b_merge,
    const float* W_ih, const float* b_ih,
    const float* W_hh, const float* b_hh,
    const float* ph,
    short* W1, float* bias1, short* W_big, float* bias_big, short* PH2e) {
  const int b = blockIdx.x, tidl = threadIdx.x;
  if (b < 64) {
    int tid = b * 256 + tidl, stride = 64 * 256;
    for (int i = tid; i < 512 * 128; i += stride) {
      int r = i >> 7, k = i & 127;
      float v;
      if (r < 128)      v = Wq[r * 128 + k];
      else if (r < 256) v = Wk[(r - 128) * 128 + k];
      else if (r < 384) v = Wv[(r - 256) * 128 + k];
      else if (r < 484) v = W_loc[(r - 384) * 128 + k];
      else              v = 0.f;
      W1[i] = f2bf(v);
    }
    for (int i = tid; i < 512; i += stride) {
      float v;
      if (i < 128)      v = bq[i];
      else if (i < 256) v = bk[i - 128];
      else if (i < 384) v = bv[i - 256];
      else if (i < 484) v = b_loc[i - 384];
      else              v = 0.f;
      bias1[i] = v;
    }
  } else if (b < 576) {
    __shared__ float rowj[128];
    const int n = b - 64;                       // 0..511
    if (tidl < 128) rowj[tidl] = (n < 384) ? W_ih[n * 224 + tidl] : 0.f;
    __syncthreads();
    {
      float acc = 0.f;
      if (n < 384) {
#pragma unroll 8
        for (int j = 0; j < 128; ++j) acc += rowj[j] * W_merge[j * 256 + tidl];
      }
      if (tidl < 128) {
        if (n < 256)      acc += W_hh[n * 128 + tidl];          // gate sum
        else if (n >= 384) acc = W_hh[(n - 128) * 128 + tidl];   // hn row
      }
      W_big[n * 384 + tidl] = f2bf(acc);
    }
    if (tidl < 128) {
      int k2 = 256 + tidl;
      float v = 0.f;
      if (n < 384) {
        if (k2 < 320)      v = W_ih[n * 224 + 128 + (k2 - 256)];   // spatial
        else if (k2 < 352) v = W_ih[n * 224 + 192 + (k2 - 320)];   // time
      }
      W_big[n * 384 + k2] = f2bf(v);
    }
    if (tidl < 64) {
      float p = rowj[tidl] * b_merge[tidl] + rowj[tidl + 64] * b_merge[tidl + 64];
#pragma unroll
      for (int mk = 1; mk < 64; mk <<= 1) p += __shfl_xor(p, mk);
      if (tidl == 0) {
        float bb;
        if (n < 256)      bb = b_ih[n] + p + b_hh[n];
        else if (n < 384) bb = b_ih[n] + p;
        else              bb = b_hh[n - 128];
        bias_big[n] = bb;
      }
    }
  } else {
    int tid = (b - 576) * 256 + tidl, stride = 1024 * 256;
    for (int i = tid; i < N_P * H_D; i += stride) {
      int r = i >> 7, d = i & 127;
      PH2e[r * LDE + d] = f2bf(ph[i]);
    }
    const float t0 = t[0];
    for (int i = tid; i < N_P * 64; i += stride) {
      int r = i >> 6, j = i & 63;
      float v = (j < 32) ? (t0 * W_time[j] + b_time[j]) : 0.f;
      PH2e[r * LDE + 320 + j] = f2bf(v);
    }
  }
}

// ---------------------------------------------------------------------------
// 64x128-tile MFMA GEMM: C[M,N] = X[M,K](bf16, stride ldx) @ W[N,K]^T + bias
// 4 waves (2x2), each 32x64 (2x4 16x16 frags). 48KB LDS -> ~3 WGs/CU.
// MODE 0: q/k/loc global writes; v-tile (blockIdx.y==2) LDS-transposed -> vT.
// MODE 2: gxs bf16 (stride 512).
// ---------------------------------------------------------------------------
template <int MODE, int K>
__global__ __launch_bounds__(256, 3) void gemm64_kernel(
    const short* __restrict__ X, int ldx, const short* __restrict__ W,
    const float* __restrict__ bias,
    short* out_q, short* out_k, short* out_vT, float* out_loc,
    short* out_gx) {
  __shared__ short Xl[64 * 128];    // 16KB
  __shared__ short Wl[128 * 128];   // 32KB (reused as transpose buffer)
  const int tid = threadIdx.x;
  const int bm = blockIdx.x * 64, bn = blockIdx.y * 128;
  const int l = tid & 63, wid = tid >> 6;
  const int g = l >> 4, c = l & 15;
  const int wr = wid >> 1, wc = wid & 1;
  f32x4 acc[2][4] = {};
  constexpr int KT = K / 128;
#pragma unroll 1
  for (int kt = 0; kt < KT; ++kt) {
    const int k0 = kt * 128;
#pragma unroll
    for (int pass = 0; pass < 4; ++pass) {
      int s = tid + pass * 256;            // 0..1023
      int row = s >> 4, p = s & 15;
      int lsl = p ^ (row & 7);             // pre-swizzled source slot
      gld_lds16(X + (size_t)(bm + row) * ldx + k0 + lsl * 8, (char*)Xl + s * 16);
    }
#pragma unroll
    for (int pass = 0; pass < 8; ++pass) {
      int s = tid + pass * 256;            // 0..2047
      int row = s >> 4, p = s & 15;
      int lsl = p ^ (row & 7);
      gld_lds16(W + (size_t)(bn + row) * K + k0 + lsl * 8, (char*)Wl + s * 16);
    }
    __syncthreads();
#pragma unroll
    for (int kc = 0; kc < 4; ++kc) {
      bf16x8 a[2], bfr[4];
#pragma unroll
      for (int mi = 0; mi < 2; ++mi)
        a[mi] = *(const bf16x8*)((const char*)Xl + swzb(wr * 32 + mi * 16 + c, kc * 4 + g, 16));
#pragma unroll
      for (int ni = 0; ni < 4; ++ni)
        bfr[ni] = *(const bf16x8*)((const char*)Wl + swzb(wc * 64 + ni * 16 + c, kc * 4 + g, 16));
#pragma unroll
      for (int mi = 0; mi < 2; ++mi)
#pragma unroll
        for (int ni = 0; ni < 4; ++ni)
          acc[mi][ni] = __builtin_amdgcn_mfma_f32_16x16x32_bf16(a[mi], bfr[ni], acc[mi][ni], 0, 0, 0);
    }
    if (kt + 1 < KT) __syncthreads();
  }
  if constexpr (MODE == 0) {
    if (blockIdx.y == 2) {
      // ---- v panel: LDS transpose -> vT[d][bm..bm+64), coalesced ----
      __syncthreads();                       // done reading Wl
      short* T = Wl;                         // 64 x 130 (pad 2 -> conflict-free)
#pragma unroll
      for (int mi = 0; mi < 2; ++mi)
#pragma unroll
        for (int ni = 0; ni < 4; ++ni)
#pragma unroll
          for (int r = 0; r < 4; ++r) {
            int rl = wr * 32 + mi * 16 + 4 * g + r;    // 0..63
            int cl = wc * 64 + ni * 16 + c;            // 0..127
            T[rl * 130 + cl] = f2bf(acc[mi][ni][r] + bias[256 + cl]);
          }
      __syncthreads();
#pragma unroll
      for (int pass = 0; pass < 32; ++pass) {
        int d = pass * 4 + (tid >> 6);
        int j = tid & 63;
        out_vT[(size_t)d * N_P + bm + j] = T[j * 130 + d];
      }
    } else {
#pragma unroll
      for (int mi = 0; mi < 2; ++mi)
#pragma unroll
        for (int ni = 0; ni < 4; ++ni)
#pragma unroll
          for (int r = 0; r < 4; ++r) {
            int row = bm + wr * 32 + mi * 16 + 4 * g + r;
            int col = bn + wc * 64 + ni * 16 + c;
            float val = acc[mi][ni][r] + bias[col];
            if (col < 128)      out_q[row * 128 + col] = f2bf(val * QSCALE);
            else if (col < 256) out_k[row * 128 + col - 128] = f2bf(val);
            else if (col >= 384 && col < 484) out_loc[row * 112 + col - 384] = val;
          }
    }
  } else {
#pragma unroll
    for (int mi = 0; mi < 2; ++mi)
#pragma unroll
      for (int ni = 0; ni < 4; ++ni)
#pragma unroll
        for (int r = 0; r < 4; ++r) {
          int row = bm + wr * 32 + mi * 16 + 4 * g + r;
          int col = bn + wc * 64 + ni * 16 + c;
          out_gx[row * 512 + col] = f2bf(acc[mi][ni][r] + bias[col]);
        }
  }
}

// ---------------------------------------------------------------------------
// Flash attention (round-10 version, proven). Grid: 64 q-blocks x 8 chunks.
// 4-wave WGs, 2 WGs/CU; K+V double-buffered; one drain+barrier per tile;
// frozen tile-0 max; denom via ones-column MFMA.
// ---------------------------------------------------------------------------
__global__ __launch_bounds__(256, 2) void attn_kernel(
    const short* __restrict__ qb, const short* __restrict__ kb,
    const short* __restrict__ vT, short* __restrict__ pacc,
    float* __restrict__ pml) {
  __shared__ short Kl[2][KVB * H_D];     // [64 kv][128 d], 16-slot swizzle, 16KB each
  __shared__ short Vl[2][H_D * KVB];     // [128 d][64 kv], 8-slot swizzle, 16KB each
  const int tid = threadIdx.x;
  const int qbk = blockIdx.x >> 3, ch = blockIdx.x & 7;
  const int chbase = ch * CHLEN;
  const int l = tid & 63, wid = tid >> 6;
  const int c32 = l & 31, hi = l >> 5;
  const int qrow0w = qbk * 128 + wid * 32;

  char* ldsK = (char*)&Kl[0][0];
  char* ldsV = (char*)&Vl[0][0];

  auto stage = [&](int b, int tt) {
    const int off = tt * KVB;
#pragma unroll
    for (int j = 0; j < 4; ++j) {
      const int i = tid + j * 256;                    // 0..1023
      const int kr = i >> 4, ks = (i & 15) ^ (kr & 15);   // 16-slot swizzle
      gld_lds16(kb + (size_t)(chbase + off + kr) * 128 + ks * 8,
                ldsK + b * 16384 + i * 16);
      const int vr = i >> 3, vs = (i & 7) ^ (vr & 7);
      gld_lds16(vT + (size_t)vr * N_P + chbase + off + vs * 8,
                ldsV + b * 16384 + i * 16);
    }
  };

  bf16x8 qf[8];
#pragma unroll
  for (int sl = 0; sl < 8; ++sl)
    qf[sl] = *(const bf16x8*)(qb + (size_t)(qrow0w + c32) * 128 + sl * 16 + hi * 8);

  bf16x8 ones;
#pragma unroll
  for (int j = 0; j < 8; ++j) ones[j] = (short)0x3F80;  // bf16 1.0

  // ---- precomputed swizzled LDS read addresses (lane-constant) ----
  const int c15 = c32 & 15;
  const int kbase0 = c32 * 256;
  int koff[8];
#pragma unroll
  for (int sl = 0; sl < 8; ++sl) koff[sl] = ((2 * sl + hi) ^ c15) << 4;
  const int xh = (c32 >> 1) & 3, x0 = c32 & 1;
  const int xb = (hi ^ x0) << 4;
  int voff[4], vbase[4];
#pragma unroll
  for (int s4 = 0; s4 < 4; ++s4) voff[s4] = (s4 ^ xh) << 5;
#pragma unroll
  for (int db = 0; db < 4; ++db) vbase[db] = (db * 32 + c32) * 128 + xb;

  f32x16 acc[4] = {};
  f32x16 accl = {};
  float m = -1e30f;

  stage(0, 0);
  asm volatile("s_waitcnt vmcnt(0)" ::: "memory");
  __builtin_amdgcn_s_barrier();
  int cur = 0;

#pragma unroll 1
  for (int t = 0; t < NTIL; ++t) {
    if (t + 1 < NTIL) stage(cur ^ 1, t + 1);

    const int kv0 = chbase + t * KVB;
    const char* Kb = (const char*)&Kl[cur][0];
    const char* Vb = (const char*)&Vl[cur][0];

    // ---- S^T = K @ Q^T ----
    f32x16 s0 = {}, s1 = {};
    __builtin_amdgcn_s_setprio(1);
#pragma unroll
    for (int sl = 0; sl < 8; ++sl) {
      bf16x8 k0 = *(const bf16x8*)(Kb + kbase0 + koff[sl]);
      bf16x8 k1 = *(const bf16x8*)(Kb + kbase0 + 8192 + koff[sl]);
      s0 = __builtin_amdgcn_mfma_f32_32x32x16_bf16(k0, qf[sl], s0, 0, 0, 0);
      s1 = __builtin_amdgcn_mfma_f32_32x32x16_bf16(k1, qf[sl], s1, 0, 0, 0);
    }
    __builtin_amdgcn_s_setprio(0);

    // ---- diagonal mask ----
    if (qrow0w + 32 > kv0 && qrow0w < kv0 + 64) {
      const int qr = qrow0w + c32;
#pragma unroll
      for (int r = 0; r < 16; ++r) {
        const int rowp = (r & 3) + 8 * (r >> 2) + 4 * hi;
        s0[r] = (kv0 + rowp == qr) ? -1e30f : s0[r];
        s1[r] = (kv0 + 32 + rowp == qr) ? -1e30f : s1[r];
      }
    }

    // ---- tile 0 only: per-q-row max, then freeze m ----
    if (t == 0) {
      f32x16 mx;
#pragma unroll
      for (int r = 0; r < 16; ++r) mx[r] = fmaxf(s0[r], s1[r]);
#pragma unroll
      for (int w2 = 8; w2 >= 1; w2 >>= 1)
#pragma unroll
        for (int r = 0; r < w2; ++r) mx[r] = fmaxf(mx[r], mx[r + w2]);
      m = fmaxf(mx[0], __shfl_xor(mx[0], 32));
    }

    // ---- P = exp2(S - m) ----
#pragma unroll
    for (int r = 0; r < 16; ++r) s0[r] = EXP2(s0[r] - m);
#pragma unroll
    for (int r = 0; r < 16; ++r) s1[r] = EXP2(s1[r] - m);

    // ---- O += P @ V ; l += P @ 1 ----
    auto pvslice = [&](const f32x16& ss, int base, int sl4) {
      unsigned dA = cvtpk(ss[base + 0], ss[base + 1]);
      unsigned dB = cvtpk(ss[base + 2], ss[base + 3]);
      unsigned dC = cvtpk(ss[base + 4], ss[base + 5]);
      unsigned dD = cvtpk(ss[base + 6], ss[base + 7]);
      swap32(dA, dC);
      swap32(dB, dD);
      uint4v w = {dA, dB, dC, dD};
      bf16x8 pa = __builtin_bit_cast(bf16x8, w);
#pragma unroll
      for (int db = 0; db < 4; ++db) {
        bf16x8 vfr = *(const bf16x8*)(Vb + vbase[db] + voff[sl4]);
        acc[db] = __builtin_amdgcn_mfma_f32_32x32x16_bf16(pa, vfr, acc[db], 0, 0, 0);
      }
      accl = __builtin_amdgcn_mfma_f32_32x32x16_bf16(pa, ones, accl, 0, 0, 0);
    };
    __builtin_amdgcn_s_setprio(1);
    pvslice(s0, 0, 0);
    pvslice(s0, 8, 1);
    pvslice(s1, 0, 2);
    pvslice(s1, 8, 3);
    __builtin_amdgcn_s_setprio(0);

    if (t + 1 < NTIL) {
      asm volatile("s_waitcnt vmcnt(0)" ::: "memory");
      __builtin_amdgcn_s_barrier();
      asm volatile("" ::: "memory");
    }
    cur ^= 1;
  }

  // ---- write partials ----
#pragma unroll
  for (int db = 0; db < 4; ++db)
#pragma unroll
    for (int r = 0; r < 16; ++r) {
      const int qr = qrow0w + (r & 3) + 8 * (r >> 2) + 4 * hi;
      pacc[((size_t)ch * N_P + qr) * 128 + db * 32 + c32] = f2bf(acc[db][r]);
    }
  {
    const int rr = (c32 & 3) | (((c32 >> 3) & 3) << 2);
    float own = (((c32 >> 2) & 1) == hi) ? accl[rr] : 0.f;
    float lv = own + __shfl_xor(own, 32);
    if (hi == 0) {
      const int qr = qrow0w + c32;
      pml[((size_t)ch * N_P + qr) * 2]     = m;
      pml[((size_t)ch * N_P + qr) * 2 + 1] = lv;
    }
  }
}

// ---------------------------------------------------------------------------
// fused: blocks [0,4096) combine chunk partials -> PH2e cols 128..255;
// blocks [4096,6144) zone softmax + spatial context -> PH2e cols 256..319
// ---------------------------------------------------------------------------
__global__ __launch_bounds__(256) void combine_spatial_kernel(
    const short* __restrict__ pacc, const float* __restrict__ pml,
    const float* __restrict__ locf, const float* __restrict__ E,
    short* __restrict__ PH2e) {
  const int b = blockIdx.x, tid = threadIdx.x;
  if (b < 4096) {
    int row = b * 2 + (tid >> 7);
    int d = tid & 127;
    float mv[NCHNK], lv[NCHNK], M = -1e30f;
#pragma unroll
    for (int cc = 0; cc < NCHNK; ++cc) {
      mv[cc] = pml[(cc * N_P + row) * 2];
      lv[cc] = pml[(cc * N_P + row) * 2 + 1];
      M = fmaxf(M, mv[cc]);
    }
    float L = 0.f, O = 0.f;
#pragma unroll
    for (int cc = 0; cc < NCHNK; ++cc) {
      float w = EXP2(mv[cc] - M);
      L += lv[cc] * w;
      O += bf2f(pacc[((size_t)cc * N_P + row) * 128 + d]) * w;
    }
    PH2e[row * LDE + 128 + d] = f2bf(O / L);
  } else {
    __shared__ float pl[4][104];
    int wid = tid >> 6, l = tid & 63;
    int row = (b - 4096) * 4 + wid;
    float v0 = locf[row * 112 + l];
    float v1 = (l + 64 < 100) ? locf[row * 112 + 64 + l] : -1e30f;
    float m = fmaxf(v0, v1);
#pragma unroll
    for (int mk = 1; mk < 64; mk <<= 1) m = fmaxf(m, __shfl_xor(m, mk));
    float p0 = EXP2((v0 - m) * LOG2E);
    float p1 = (l + 64 < 100) ? EXP2((v1 - m) * LOG2E) : 0.f;
    float s = p0 + p1;
#pragma unroll
    for (int mk = 1; mk < 64; mk <<= 1) s += __shfl_xor(s, mk);
    float inv = 1.f / s;
    pl[wid][l] = p0 * inv;
    if (l + 64 < 100) pl[wid][64 + l] = p1 * inv;
    float acc = 0.f;
#pragma unroll 4
    for (int z = 0; z < 100; ++z) acc += pl[wid][z] * E[z * 64 + l];
    PH2e[row * LDE + 256 + l] = f2bf(acc);
  }
}

// ---------------------------------------------------------------------------
// GRU gates + d = (1-z)(ng-h) + LayerNorm. One wave per row; thread handles
// adjacent d-pair (2l, 2l+1) -> dword gate loads, float2 ph/out.
// gxs per row (512): [0,128)=xr+hr, [128,256)=xz+hz, [256,384)=xn, [384,512)=hn
// ---------------------------------------------------------------------------
__global__ __launch_bounds__(256) void final_kernel(const short* __restrict__ gxs,
                                                    const float* __restrict__ ph,
                                                    const float* __restrict__ gamma,
                                                    const float* __restrict__ beta,
                                                    float* __restrict__ out) {
  int tid = threadIdx.x, wid = tid >> 6, l = tid & 63;
  int row = blockIdx.x * 4 + wid;
  const int d0 = 2 * l;
  const short* gr = gxs + (size_t)row * 512 + d0;
  unsigned usr = *(const unsigned*)(gr);
  unsigned usz = *(const unsigned*)(gr + 128);
  unsigned uxn = *(const unsigned*)(gr + 256);
  unsigned uhn = *(const unsigned*)(gr + 384);
  float2 hh = *(const float2*)(ph + (size_t)row * 128 + d0);
  float dd[2];
#pragma unroll
  for (int j = 0; j < 2; ++j) {
    float sr = bf2f((short)(j ? (usr >> 16) : (usr & 0xffffu)));
    float sz = bf2f((short)(j ? (usz >> 16) : (usz & 0xffffu)));
    float xn = bf2f((short)(j ? (uxn >> 16) : (uxn & 0xffffu)));
    float hn = bf2f((short)(j ? (uhn >> 16) : (uhn & 0xffffu)));
    float h = j ? hh.y : hh.x;
    float r = 1.f / (1.f + EXP2(-LOG2E * sr));
    float z = 1.f / (1.f + EXP2(-LOG2E * sz));
    float a = xn + r * hn;
    float ng = 1.f - 2.f / (1.f + EXP2(2.f * LOG2E * a));  // tanh(a)
    dd[j] = (1.f - z) * (ng - h);
  }
  float s = dd[0] + dd[1], ss = dd[0] * dd[0] + dd[1] * dd[1];
#pragma unroll
  for (int mk = 1; mk < 64; mk <<= 1) {
    s += __shfl_xor(s, mk);
    ss += __shfl_xor(ss, mk);
  }
  float mu = s * (1.f / 128.f);
  float var = ss * (1.f / 128.f) - mu * mu;
  float rs = rsqrtf(var + 1e-5f);
  float2 gm = *(const float2*)(gamma + d0);
  float2 bt = *(const float2*)(beta + d0);
  float2 o;
  o.x = (dd[0] - mu) * rs * gm.x + bt.x;
  o.y = (dd[1] - mu) * rs * gm.y + bt.y;
  *(float2*)(out + (size_t)row * 128 + d0) = o;
}

// ---------------------------------------------------------------------------
extern "C" void kernel_launch(void* const* d_in, const int* in_sizes, int n_in,
                              void* d_out, int out_size, void* d_ws, size_t ws_size,
                              hipStream_t stream) {
  const float* t       = (const float*)d_in[0];
  const float* ph      = (const float*)d_in[1];
  const float* E       = (const float*)d_in[2];
  const float* W_time  = (const float*)d_in[3];
  const float* b_time  = (const float*)d_in[4];
  const float* W_loc   = (const float*)d_in[5];
  const float* b_loc   = (const float*)d_in[6];
  const float* Wq      = (const float*)d_in[7];
  const float* bq      = (const float*)d_in[8];
  const float* Wk      = (const float*)d_in[9];
  const float* bk      = (const float*)d_in[10];
  const float* Wv      = (const float*)d_in[11];
  const float* bv      = (const float*)d_in[12];
  const float* W_merge = (const float*)d_in[13];
  const float* b_merge = (const float*)d_in[14];
  const float* W_ih    = (const float*)d_in[15];
  const float* b_ih    = (const float*)d_in[16];
  const float* W_hh    = (const float*)d_in[17];
  const float* b_hh    = (const float*)d_in[18];
  const float* gamma   = (const float*)d_in[19];
  const float* beta    = (const float*)d_in[20];
  float* out = (float*)d_out;

  char* w = (char*)d_ws;
  auto alloc = [&](size_t bytes) {
    char* p = w;
    w += (bytes + 255) & ~(size_t)255;
    return p;
  };
  short* W1      = (short*)alloc(512 * 128 * 2);
  float* bias1   = (float*)alloc(512 * 4);
  short* W_big   = (short*)alloc(512 * 384 * 2);
  float* bias_big= (float*)alloc(512 * 4);
  short* PH2e    = (short*)alloc((size_t)N_P * LDE * 2);
  short* qbuf    = (short*)alloc((size_t)N_P * 128 * 2);
  short* kbuf    = (short*)alloc((size_t)N_P * 128 * 2);
  short* vT      = (short*)alloc((size_t)128 * N_P * 2);
  float* locf    = (float*)alloc((size_t)N_P * 112 * 4);
  short* gxs     = (short*)alloc((size_t)N_P * 512 * 2);
  short* pacc    = (short*)alloc((size_t)NCHNK * N_P * 128 * 2);
  float* pml     = (float*)alloc((size_t)NCHNK * N_P * 2 * 4);

  init_kernel<<<1600, 256, 0, stream>>>(t, W_time, b_time, W_loc, b_loc, Wq, bq,
                                        Wk, bk, Wv, bv, W_merge, b_merge,
                                        W_ih, b_ih, W_hh, b_hh, ph,
                                        W1, bias1, W_big, bias_big, PH2e);
  gemm64_kernel<0, 128><<<dim3(128, 4), 256, 0, stream>>>(
      PH2e, LDE, W1, bias1, qbuf, kbuf, vT, locf, nullptr);
  attn_kernel<<<512, 256, 0, stream>>>(qbuf, kbuf, vT, pacc, pml);
  combine_spatial_kernel<<<6144, 256, 0, stream>>>(pacc, pml, locf, E, PH2e);
  gemm64_kernel<2, 384><<<dim3(128, 4), 256, 0, stream>>>(
      PH2e, LDE, W_big, bias_big, nullptr, nullptr, nullptr, nullptr, gxs);
  final_kernel<<<2048, 256, 0, stream>>>(gxs, ph, gamma, beta, out);
}

// Round 13
// 88.219 us; speedup vs baseline: 1.1057x; 1.0078x over previous
//
#include <hip/hip_runtime.h>

// ---------------------------------------------------------------------------
// HouseholdODEFunc: soft-location context + leave-one-out attention + GRU + LN
// N=8192 people, H=128. All heavy matmuls in bf16 MFMA, fp32 accum.
// Attention: round-10 kernel (frozen at 44.5us, 2 WGs/CU plateau).
// This round: XCD-bijective swizzle on both GEMMs (each XCD owns a contiguous
// bm slice -> X re-reads hit its own L2), vectorized combine (int/float2),
// vectorized init prep (float4 -> short8).
// ---------------------------------------------------------------------------

typedef __attribute__((ext_vector_type(8)))  short bf16x8;
typedef __attribute__((ext_vector_type(4)))  float f32x4;
typedef __attribute__((ext_vector_type(16))) float f32x16;
typedef __attribute__((ext_vector_type(4)))  unsigned uint4v;

#define N_P   8192
#define H_D   128
#define NCHNK 8
#define CHLEN (N_P / NCHNK)    // 1024 kv per chunk
#define KVB   64
#define NTIL  (CHLEN / KVB)    // 16 tiles per chunk
#define LDE   384              // PH2e row stride: ph(128)|social(128)|spatial(64)|time(32)|pad(32)

#if __has_builtin(__builtin_amdgcn_exp2f)
#define EXP2(x) __builtin_amdgcn_exp2f(x)
#else
#define EXP2(x) exp2f(x)
#endif

__device__ __forceinline__ short f2bf(float f) {   // RNE float->bf16 bits
  unsigned u = __float_as_uint(f);
  u = (u + 0x7fffu + ((u >> 16) & 1u)) >> 16;
  return (short)u;
}
__device__ __forceinline__ float bf2f(short s) {
  return __uint_as_float(((unsigned)(unsigned short)s) << 16);
}
__device__ __forceinline__ unsigned pack2bf(float a, float b) {
  return (unsigned)(unsigned short)f2bf(a) | ((unsigned)(unsigned short)f2bf(b) << 16);
}

// XOR-swizzled byte offset of a 16B slot in a row-major LDS tile.
__device__ __forceinline__ int swzb(int row, int slot, int nslots) {
  return (row * nslots + (slot ^ (row & ((nslots - 1) & 7)))) << 4;
}

__device__ __forceinline__ unsigned cvtpk(float a, float b) {
  unsigned d;
  asm("v_cvt_pk_bf16_f32 %0, %1, %2" : "=v"(d) : "v"(a), "v"(b));
  return d;
}

__device__ __forceinline__ void swap32(unsigned& a, unsigned& b) {
#if __has_builtin(__builtin_amdgcn_permlane32_swap)
  auto r = __builtin_amdgcn_permlane32_swap(a, b, false, false);
  a = r[0]; b = r[1];
#else
  asm volatile("v_permlane32_swap_b32 %0, %1" : "+v"(a), "+v"(b));
#endif
}

typedef __attribute__((address_space(1))) const void GV;
typedef __attribute__((address_space(3))) void LV;
__device__ __forceinline__ void gld_lds16(const void* g, void* l) {
  __builtin_amdgcn_global_load_lds((GV*)g, (LV*)l, 16, 0, 0);
}

__constant__ const float QSCALE = 0.12751551485988857f; // log2(e)/sqrt(128)
#define LOG2E 1.4426950408889634f

// ---------------------------------------------------------------------------
// init: W1/bias1 pack (512 rows: q,k,v,loc) + W_big/bias_big fold + PH2e prep
// blocks [0,64): pack; [64,576): W_big row per WG; [576,704): prep (vectorized)
// ---------------------------------------------------------------------------
__global__ __launch_bounds__(256) void init_kernel(
    const float* t, const float* W_time, const float* b_time,
    const float* W_loc, const float* b_loc,
    const float* Wq, const float* bq, const float* Wk, const float* bk,
    const float* Wv, const float* bv,
    const float* W_merge, const float* b_merge,
    const float* W_ih, const float* b_ih,
    const float* W_hh, const float* b_hh,
    const float* ph,
    short* W1, float* bias1, short* W_big, float* bias_big, short* PH2e) {
  const int b = blockIdx.x, tidl = threadIdx.x;
  if (b < 64) {
    int tid = b * 256 + tidl, stride = 64 * 256;
    for (int i = tid; i < 512 * 128; i += stride) {
      int r = i >> 7, k = i & 127;
      float v;
      if (r < 128)      v = Wq[r * 128 + k];
      else if (r < 256) v = Wk[(r - 128) * 128 + k];
      else if (r < 384) v = Wv[(r - 256) * 128 + k];
      else if (r < 484) v = W_loc[(r - 384) * 128 + k];
      else              v = 0.f;
      W1[i] = f2bf(v);
    }
    for (int i = tid; i < 512; i += stride) {
      float v;
      if (i < 128)      v = bq[i];
      else if (i < 256) v = bk[i - 128];
      else if (i < 384) v = bv[i - 256];
      else if (i < 484) v = b_loc[i - 384];
      else              v = 0.f;
      bias1[i] = v;
    }
  } else if (b < 576) {
    __shared__ float rowj[128];
    const int n = b - 64;                       // 0..511
    if (tidl < 128) rowj[tidl] = (n < 384) ? W_ih[n * 224 + tidl] : 0.f;
    __syncthreads();
    {
      float acc = 0.f;
      if (n < 384) {
#pragma unroll 8
        for (int j = 0; j < 128; ++j) acc += rowj[j] * W_merge[j * 256 + tidl];
      }
      if (tidl < 128) {
        if (n < 256)      acc += W_hh[n * 128 + tidl];          // gate sum
        else if (n >= 384) acc = W_hh[(n - 128) * 128 + tidl];   // hn row
      }
      W_big[n * 384 + tidl] = f2bf(acc);
    }
    if (tidl < 128) {
      int k2 = 256 + tidl;
      float v = 0.f;
      if (n < 384) {
        if (k2 < 320)      v = W_ih[n * 224 + 128 + (k2 - 256)];   // spatial
        else if (k2 < 352) v = W_ih[n * 224 + 192 + (k2 - 320)];   // time
      }
      W_big[n * 384 + k2] = f2bf(v);
    }
    if (tidl < 64) {
      float p = rowj[tidl] * b_merge[tidl] + rowj[tidl + 64] * b_merge[tidl + 64];
#pragma unroll
      for (int mk = 1; mk < 64; mk <<= 1) p += __shfl_xor(p, mk);
      if (tidl == 0) {
        float bb;
        if (n < 256)      bb = b_ih[n] + p + b_hh[n];
        else if (n < 384) bb = b_ih[n] + p;
        else              bb = b_hh[n - 128];
        bias_big[n] = bb;
      }
    }
  } else {
    // prep (vectorized 8 elems/thread): blocks [576, 704)
    int tid = (b - 576) * 256 + tidl, stride = 128 * 256;
    for (int i = tid; i < N_P * 16; i += stride) {
      int r = i >> 4, d8 = (i & 15) * 8;
      float4 a  = *(const float4*)(ph + (size_t)r * 128 + d8);
      float4 a2 = *(const float4*)(ph + (size_t)r * 128 + d8 + 4);
      int4 o;
      o.x = (int)pack2bf(a.x,  a.y);
      o.y = (int)pack2bf(a.z,  a.w);
      o.z = (int)pack2bf(a2.x, a2.y);
      o.w = (int)pack2bf(a2.z, a2.w);
      *(int4*)(PH2e + (size_t)r * LDE + d8) = o;
    }
    const float t0 = t[0];
    for (int i = tid; i < N_P * 8; i += stride) {
      int r = i >> 3, j8 = (i & 7) * 8;
      float v[8];
#pragma unroll
      for (int k = 0; k < 8; ++k) {
        int j = j8 + k;
        v[k] = (j < 32) ? (t0 * W_time[j] + b_time[j]) : 0.f;
      }
      int4 o;
      o.x = (int)pack2bf(v[0], v[1]);
      o.y = (int)pack2bf(v[2], v[3]);
      o.z = (int)pack2bf(v[4], v[5]);
      o.w = (int)pack2bf(v[6], v[7]);
      *(int4*)(PH2e + (size_t)r * LDE + 320 + j8) = o;
    }
  }
}

// ---------------------------------------------------------------------------
// 64x128-tile MFMA GEMM: C[M,N] = X[M,K](bf16, stride ldx) @ W[N,K]^T + bias
// 4 waves (2x2), each 32x64 (2x4 16x16 frags). 48KB LDS -> ~3 WGs/CU.
// XCD-bijective tile remap: xcd = lin%8 owns bm in [xcd*16, xcd*16+16) for
// all 4 bn passes -> X re-reads hit that XCD's private L2.
// MODE 0: q/k/loc global writes; v-tile (bnIdx==2) LDS-transposed -> vT.
// MODE 2: gxs bf16 (stride 512).
// ---------------------------------------------------------------------------
template <int MODE, int K>
__global__ __launch_bounds__(256, 3) void gemm64_kernel(
    const short* __restrict__ X, int ldx, const short* __restrict__ W,
    const float* __restrict__ bias,
    short* out_q, short* out_k, short* out_vT, float* out_loc,
    short* out_gx) {
  __shared__ short Xl[64 * 128];    // 16KB
  __shared__ short Wl[128 * 128];   // 32KB (reused as transpose buffer)
  const int tid = threadIdx.x;
  // XCD-aware remap of the 512-block grid (gridDim = (128,4), x fastest)
  const int lin = blockIdx.y * 128 + blockIdx.x;
  const int xcd = lin & 7, j = lin >> 3;
  const int bmIdx = xcd * 16 + (j & 15);
  const int bnIdx = j >> 4;
  const int bm = bmIdx * 64, bn = bnIdx * 128;
  const int l = tid & 63, wid = tid >> 6;
  const int g = l >> 4, c = l & 15;
  const int wr = wid >> 1, wc = wid & 1;
  f32x4 acc[2][4] = {};
  constexpr int KT = K / 128;
#pragma unroll 1
  for (int kt = 0; kt < KT; ++kt) {
    const int k0 = kt * 128;
#pragma unroll
    for (int pass = 0; pass < 4; ++pass) {
      int s = tid + pass * 256;            // 0..1023
      int row = s >> 4, p = s & 15;
      int lsl = p ^ (row & 7);             // pre-swizzled source slot
      gld_lds16(X + (size_t)(bm + row) * ldx + k0 + lsl * 8, (char*)Xl + s * 16);
    }
#pragma unroll
    for (int pass = 0; pass < 8; ++pass) {
      int s = tid + pass * 256;            // 0..2047
      int row = s >> 4, p = s & 15;
      int lsl = p ^ (row & 7);
      gld_lds16(W + (size_t)(bn + row) * K + k0 + lsl * 8, (char*)Wl + s * 16);
    }
    __syncthreads();
#pragma unroll
    for (int kc = 0; kc < 4; ++kc) {
      bf16x8 a[2], bfr[4];
#pragma unroll
      for (int mi = 0; mi < 2; ++mi)
        a[mi] = *(const bf16x8*)((const char*)Xl + swzb(wr * 32 + mi * 16 + c, kc * 4 + g, 16));
#pragma unroll
      for (int ni = 0; ni < 4; ++ni)
        bfr[ni] = *(const bf16x8*)((const char*)Wl + swzb(wc * 64 + ni * 16 + c, kc * 4 + g, 16));
#pragma unroll
      for (int mi = 0; mi < 2; ++mi)
#pragma unroll
        for (int ni = 0; ni < 4; ++ni)
          acc[mi][ni] = __builtin_amdgcn_mfma_f32_16x16x32_bf16(a[mi], bfr[ni], acc[mi][ni], 0, 0, 0);
    }
    if (kt + 1 < KT) __syncthreads();
  }
  if constexpr (MODE == 0) {
    if (bnIdx == 2) {
      // ---- v panel: LDS transpose -> vT[d][bm..bm+64), coalesced ----
      __syncthreads();                       // done reading Wl
      short* T = Wl;                         // 64 x 130 (pad 2 -> conflict-free)
#pragma unroll
      for (int mi = 0; mi < 2; ++mi)
#pragma unroll
        for (int ni = 0; ni < 4; ++ni)
#pragma unroll
          for (int r = 0; r < 4; ++r) {
            int rl = wr * 32 + mi * 16 + 4 * g + r;    // 0..63
            int cl = wc * 64 + ni * 16 + c;            // 0..127
            T[rl * 130 + cl] = f2bf(acc[mi][ni][r] + bias[256 + cl]);
          }
      __syncthreads();
#pragma unroll
      for (int pass = 0; pass < 32; ++pass) {
        int d = pass * 4 + (tid >> 6);
        int jj = tid & 63;
        out_vT[(size_t)d * N_P + bm + jj] = T[jj * 130 + d];
      }
    } else {
#pragma unroll
      for (int mi = 0; mi < 2; ++mi)
#pragma unroll
        for (int ni = 0; ni < 4; ++ni)
#pragma unroll
          for (int r = 0; r < 4; ++r) {
            int row = bm + wr * 32 + mi * 16 + 4 * g + r;
            int col = bn + wc * 64 + ni * 16 + c;
            float val = acc[mi][ni][r] + bias[col];
            if (col < 128)      out_q[row * 128 + col] = f2bf(val * QSCALE);
            else if (col < 256) out_k[row * 128 + col - 128] = f2bf(val);
            else if (col >= 384 && col < 484) out_loc[row * 112 + col - 384] = val;
          }
    }
  } else {
#pragma unroll
    for (int mi = 0; mi < 2; ++mi)
#pragma unroll
      for (int ni = 0; ni < 4; ++ni)
#pragma unroll
        for (int r = 0; r < 4; ++r) {
          int row = bm + wr * 32 + mi * 16 + 4 * g + r;
          int col = bn + wc * 64 + ni * 16 + c;
          out_gx[row * 512 + col] = f2bf(acc[mi][ni][r] + bias[col]);
        }
  }
}

// ---------------------------------------------------------------------------
// Flash attention (round-10 version, FROZEN). Grid: 64 q-blocks x 8 chunks.
// 4-wave WGs, 2 WGs/CU; K+V double-buffered; one drain+barrier per tile;
// frozen tile-0 max; denom via ones-column MFMA.
// ---------------------------------------------------------------------------
__global__ __launch_bounds__(256, 2) void attn_kernel(
    const short* __restrict__ qb, const short* __restrict__ kb,
    const short* __restrict__ vT, short* __restrict__ pacc,
    float* __restrict__ pml) {
  __shared__ short Kl[2][KVB * H_D];     // [64 kv][128 d], 16-slot swizzle, 16KB each
  __shared__ short Vl[2][H_D * KVB];     // [128 d][64 kv], 8-slot swizzle, 16KB each
  const int tid = threadIdx.x;
  const int qbk = blockIdx.x >> 3, ch = blockIdx.x & 7;
  const int chbase = ch * CHLEN;
  const int l = tid & 63, wid = tid >> 6;
  const int c32 = l & 31, hi = l >> 5;
  const int qrow0w = qbk * 128 + wid * 32;

  char* ldsK = (char*)&Kl[0][0];
  char* ldsV = (char*)&Vl[0][0];

  auto stage = [&](int b, int tt) {
    const int off = tt * KVB;
#pragma unroll
    for (int j = 0; j < 4; ++j) {
      const int i = tid + j * 256;                    // 0..1023
      const int kr = i >> 4, ks = (i & 15) ^ (kr & 15);   // 16-slot swizzle
      gld_lds16(kb + (size_t)(chbase + off + kr) * 128 + ks * 8,
                ldsK + b * 16384 + i * 16);
      const int vr = i >> 3, vs = (i & 7) ^ (vr & 7);
      gld_lds16(vT + (size_t)vr * N_P + chbase + off + vs * 8,
                ldsV + b * 16384 + i * 16);
    }
  };

  bf16x8 qf[8];
#pragma unroll
  for (int sl = 0; sl < 8; ++sl)
    qf[sl] = *(const bf16x8*)(qb + (size_t)(qrow0w + c32) * 128 + sl * 16 + hi * 8);

  bf16x8 ones;
#pragma unroll
  for (int j = 0; j < 8; ++j) ones[j] = (short)0x3F80;  // bf16 1.0

  // ---- precomputed swizzled LDS read addresses (lane-constant) ----
  const int c15 = c32 & 15;
  const int kbase0 = c32 * 256;
  int koff[8];
#pragma unroll
  for (int sl = 0; sl < 8; ++sl) koff[sl] = ((2 * sl + hi) ^ c15) << 4;
  const int xh = (c32 >> 1) & 3, x0 = c32 & 1;
  const int xb = (hi ^ x0) << 4;
  int voff[4], vbase[4];
#pragma unroll
  for (int s4 = 0; s4 < 4; ++s4) voff[s4] = (s4 ^ xh) << 5;
#pragma unroll
  for (int db = 0; db < 4; ++db) vbase[db] = (db * 32 + c32) * 128 + xb;

  f32x16 acc[4] = {};
  f32x16 accl = {};
  float m = -1e30f;

  stage(0, 0);
  asm volatile("s_waitcnt vmcnt(0)" ::: "memory");
  __builtin_amdgcn_s_barrier();
  int cur = 0;

#pragma unroll 1
  for (int t = 0; t < NTIL; ++t) {
    if (t + 1 < NTIL) stage(cur ^ 1, t + 1);

    const int kv0 = chbase + t * KVB;
    const char* Kb = (const char*)&Kl[cur][0];
    const char* Vb = (const char*)&Vl[cur][0];

    // ---- S^T = K @ Q^T ----
    f32x16 s0 = {}, s1 = {};
    __builtin_amdgcn_s_setprio(1);
#pragma unroll
    for (int sl = 0; sl < 8; ++sl) {
      bf16x8 k0 = *(const bf16x8*)(Kb + kbase0 + koff[sl]);
      bf16x8 k1 = *(const bf16x8*)(Kb + kbase0 + 8192 + koff[sl]);
      s0 = __builtin_amdgcn_mfma_f32_32x32x16_bf16(k0, qf[sl], s0, 0, 0, 0);
      s1 = __builtin_amdgcn_mfma_f32_32x32x16_bf16(k1, qf[sl], s1, 0, 0, 0);
    }
    __builtin_amdgcn_s_setprio(0);

    // ---- diagonal mask ----
    if (qrow0w + 32 > kv0 && qrow0w < kv0 + 64) {
      const int qr = qrow0w + c32;
#pragma unroll
      for (int r = 0; r < 16; ++r) {
        const int rowp = (r & 3) + 8 * (r >> 2) + 4 * hi;
        s0[r] = (kv0 + rowp == qr) ? -1e30f : s0[r];
        s1[r] = (kv0 + 32 + rowp == qr) ? -1e30f : s1[r];
      }
    }

    // ---- tile 0 only: per-q-row max, then freeze m ----
    if (t == 0) {
      f32x16 mx;
#pragma unroll
      for (int r = 0; r < 16; ++r) mx[r] = fmaxf(s0[r], s1[r]);
#pragma unroll
      for (int w2 = 8; w2 >= 1; w2 >>= 1)
#pragma unroll
        for (int r = 0; r < w2; ++r) mx[r] = fmaxf(mx[r], mx[r + w2]);
      m = fmaxf(mx[0], __shfl_xor(mx[0], 32));
    }

    // ---- P = exp2(S - m) ----
#pragma unroll
    for (int r = 0; r < 16; ++r) s0[r] = EXP2(s0[r] - m);
#pragma unroll
    for (int r = 0; r < 16; ++r) s1[r] = EXP2(s1[r] - m);

    // ---- O += P @ V ; l += P @ 1 ----
    auto pvslice = [&](const f32x16& ss, int base, int sl4) {
      unsigned dA = cvtpk(ss[base + 0], ss[base + 1]);
      unsigned dB = cvtpk(ss[base + 2], ss[base + 3]);
      unsigned dC = cvtpk(ss[base + 4], ss[base + 5]);
      unsigned dD = cvtpk(ss[base + 6], ss[base + 7]);
      swap32(dA, dC);
      swap32(dB, dD);
      uint4v w = {dA, dB, dC, dD};
      bf16x8 pa = __builtin_bit_cast(bf16x8, w);
#pragma unroll
      for (int db = 0; db < 4; ++db) {
        bf16x8 vfr = *(const bf16x8*)(Vb + vbase[db] + voff[sl4]);
        acc[db] = __builtin_amdgcn_mfma_f32_32x32x16_bf16(pa, vfr, acc[db], 0, 0, 0);
      }
      accl = __builtin_amdgcn_mfma_f32_32x32x16_bf16(pa, ones, accl, 0, 0, 0);
    };
    __builtin_amdgcn_s_setprio(1);
    pvslice(s0, 0, 0);
    pvslice(s0, 8, 1);
    pvslice(s1, 0, 2);
    pvslice(s1, 8, 3);
    __builtin_amdgcn_s_setprio(0);

    if (t + 1 < NTIL) {
      asm volatile("s_waitcnt vmcnt(0)" ::: "memory");
      __builtin_amdgcn_s_barrier();
      asm volatile("" ::: "memory");
    }
    cur ^= 1;
  }

  // ---- write partials ----
#pragma unroll
  for (int db = 0; db < 4; ++db)
#pragma unroll
    for (int r = 0; r < 16; ++r) {
      const int qr = qrow0w + (r & 3) + 8 * (r >> 2) + 4 * hi;
      pacc[((size_t)ch * N_P + qr) * 128 + db * 32 + c32] = f2bf(acc[db][r]);
    }
  {
    const int rr = (c32 & 3) | (((c32 >> 3) & 3) << 2);
    float own = (((c32 >> 2) & 1) == hi) ? accl[rr] : 0.f;
    float lv = own + __shfl_xor(own, 32);
    if (hi == 0) {
      const int qr = qrow0w + c32;
      pml[((size_t)ch * N_P + qr) * 2]     = m;
      pml[((size_t)ch * N_P + qr) * 2 + 1] = lv;
    }
  }
}

// ---------------------------------------------------------------------------
// fused: blocks [0,2048) combine (4 rows/block, int-pair loads) -> PH2e cols
// 128..255; blocks [2048,4096) zone softmax + spatial -> PH2e cols 256..319
// ---------------------------------------------------------------------------
__global__ __launch_bounds__(256) void combine_spatial_kernel(
    const short* __restrict__ pacc, const float* __restrict__ pml,
    const float* __restrict__ locf, const float* __restrict__ E,
    short* __restrict__ PH2e) {
  const int b = blockIdx.x, tid = threadIdx.x;
  if (b < 2048) {
    const int sub = tid >> 6;            // row within block (0..3)
    const int t6 = tid & 63;             // d-pair index
    const int row = b * 4 + sub;
    const int d0 = 2 * t6;
    float mv[NCHNK], lv[NCHNK], M = -1e30f;
#pragma unroll
    for (int cc = 0; cc < NCHNK; ++cc) {
      float2 ml = *(const float2*)(pml + ((size_t)cc * N_P + row) * 2);
      mv[cc] = ml.x; lv[cc] = ml.y;
      M = fmaxf(M, mv[cc]);
    }
    float L = 0.f, Ox = 0.f, Oy = 0.f;
#pragma unroll
    for (int cc = 0; cc < NCHNK; ++cc) {
      unsigned pp = *(const unsigned*)(pacc + ((size_t)cc * N_P + row) * 128 + d0);
      float w = EXP2(mv[cc] - M);
      L += lv[cc] * w;
      Ox += bf2f((short)(pp & 0xffffu)) * w;
      Oy += bf2f((short)(pp >> 16)) * w;
    }
    float inv = 1.f / L;
    *(unsigned*)(PH2e + (size_t)row * LDE + 128 + d0) = pack2bf(Ox * inv, Oy * inv);
  } else {
    __shared__ float pl[4][104];
    int wid = tid >> 6, l = tid & 63;
    int row = (b - 2048) * 4 + wid;
    float v0 = locf[row * 112 + l];
    float v1 = (l + 64 < 100) ? locf[row * 112 + 64 + l] : -1e30f;
    float m = fmaxf(v0, v1);
#pragma unroll
    for (int mk = 1; mk < 64; mk <<= 1) m = fmaxf(m, __shfl_xor(m, mk));
    float p0 = EXP2((v0 - m) * LOG2E);
    float p1 = (l + 64 < 100) ? EXP2((v1 - m) * LOG2E) : 0.f;
    float s = p0 + p1;
#pragma unroll
    for (int mk = 1; mk < 64; mk <<= 1) s += __shfl_xor(s, mk);
    float inv = 1.f / s;
    pl[wid][l] = p0 * inv;
    if (l + 64 < 100) pl[wid][64 + l] = p1 * inv;
    float acc = 0.f;
#pragma unroll 4
    for (int z = 0; z < 100; ++z) acc += pl[wid][z] * E[z * 64 + l];
    PH2e[row * LDE + 256 + l] = f2bf(acc);
  }
}

// ---------------------------------------------------------------------------
// GRU gates + d = (1-z)(ng-h) + LayerNorm. One wave per row; thread handles
// adjacent d-pair (2l, 2l+1) -> dword gate loads, float2 ph/out.
// gxs per row (512): [0,128)=xr+hr, [128,256)=xz+hz, [256,384)=xn, [384,512)=hn
// ---------------------------------------------------------------------------
__global__ __launch_bounds__(256) void final_kernel(const short* __restrict__ gxs,
                                                    const float* __restrict__ ph,
                                                    const float* __restrict__ gamma,
                                                    const float* __restrict__ beta,
                                                    float* __restrict__ out) {
  int tid = threadIdx.x, wid = tid >> 6, l = tid & 63;
  int row = blockIdx.x * 4 + wid;
  const int d0 = 2 * l;
  const short* gr = gxs + (size_t)row * 512 + d0;
  unsigned usr = *(const unsigned*)(gr);
  unsigned usz = *(const unsigned*)(gr + 128);
  unsigned uxn = *(const unsigned*)(gr + 256);
  unsigned uhn = *(const unsigned*)(gr + 384);
  float2 hh = *(const float2*)(ph + (size_t)row * 128 + d0);
  float dd[2];
#pragma unroll
  for (int j = 0; j < 2; ++j) {
    float sr = bf2f((short)(j ? (usr >> 16) : (usr & 0xffffu)));
    float sz = bf2f((short)(j ? (usz >> 16) : (usz & 0xffffu)));
    float xn = bf2f((short)(j ? (uxn >> 16) : (uxn & 0xffffu)));
    float hn = bf2f((short)(j ? (uhn >> 16) : (uhn & 0xffffu)));
    float h = j ? hh.y : hh.x;
    float r = 1.f / (1.f + EXP2(-LOG2E * sr));
    float z = 1.f / (1.f + EXP2(-LOG2E * sz));
    float a = xn + r * hn;
    float ng = 1.f - 2.f / (1.f + EXP2(2.f * LOG2E * a));  // tanh(a)
    dd[j] = (1.f - z) * (ng - h);
  }
  float s = dd[0] + dd[1], ss = dd[0] * dd[0] + dd[1] * dd[1];
#pragma unroll
  for (int mk = 1; mk < 64; mk <<= 1) {
    s += __shfl_xor(s, mk);
    ss += __shfl_xor(ss, mk);
  }
  float mu = s * (1.f / 128.f);
  float var = ss * (1.f / 128.f) - mu * mu;
  float rs = rsqrtf(var + 1e-5f);
  float2 gm = *(const float2*)(gamma + d0);
  float2 bt = *(const float2*)(beta + d0);
  float2 o;
  o.x = (dd[0] - mu) * rs * gm.x + bt.x;
  o.y = (dd[1] - mu) * rs * gm.y + bt.y;
  *(float2*)(out + (size_t)row * 128 + d0) = o;
}

// ---------------------------------------------------------------------------
extern "C" void kernel_launch(void* const* d_in, const int* in_sizes, int n_in,
                              void* d_out, int out_size, void* d_ws, size_t ws_size,
                              hipStream_t stream) {
  const float* t       = (const float*)d_in[0];
  const float* ph      = (const float*)d_in[1];
  const float* E       = (const float*)d_in[2];
  const float* W_time  = (const float*)d_in[3];
  const float* b_time  = (const float*)d_in[4];
  const float* W_loc   = (const float*)d_in[5];
  const float* b_loc   = (const float*)d_in[6];
  const float* Wq      = (const float*)d_in[7];
  const float* bq      = (const float*)d_in[8];
  const float* Wk      = (const float*)d_in[9];
  const float* bk      = (const float*)d_in[10];
  const float* Wv      = (const float*)d_in[11];
  const float* bv      = (const float*)d_in[12];
  const float* W_merge = (const float*)d_in[13];
  const float* b_merge = (const float*)d_in[14];
  const float* W_ih    = (const float*)d_in[15];
  const float* b_ih    = (const float*)d_in[16];
  const float* W_hh    = (const float*)d_in[17];
  const float* b_hh    = (const float*)d_in[18];
  const float* gamma   = (const float*)d_in[19];
  const float* beta    = (const float*)d_in[20];
  float* out = (float*)d_out;

  char* w = (char*)d_ws;
  auto alloc = [&](size_t bytes) {
    char* p = w;
    w += (bytes + 255) & ~(size_t)255;
    return p;
  };
  short* W1      = (short*)alloc(512 * 128 * 2);
  float* bias1   = (float*)alloc(512 * 4);
  short* W_big   = (short*)alloc(512 * 384 * 2);
  float* bias_big= (float*)alloc(512 * 4);
  short* PH2e    = (short*)alloc((size_t)N_P * LDE * 2);
  short* qbuf    = (short*)alloc((size_t)N_P * 128 * 2);
  short* kbuf    = (short*)alloc((size_t)N_P * 128 * 2);
  short* vT      = (short*)alloc((size_t)128 * N_P * 2);
  float* locf    = (float*)alloc((size_t)N_P * 112 * 4);
  short* gxs     = (short*)alloc((size_t)N_P * 512 * 2);
  short* pacc    = (short*)alloc((size_t)NCHNK * N_P * 128 * 2);
  float* pml     = (float*)alloc((size_t)NCHNK * N_P * 2 * 4);

  init_kernel<<<704, 256, 0, stream>>>(t, W_time, b_time, W_loc, b_loc, Wq, bq,
                                       Wk, bk, Wv, bv, W_merge, b_merge,
                                       W_ih, b_ih, W_hh, b_hh, ph,
                                       W1, bias1, W_big, bias_big, PH2e);
  gemm64_kernel<0, 128><<<dim3(128, 4), 256, 0, stream>>>(
      PH2e, LDE, W1, bias1, qbuf, kbuf, vT, locf, nullptr);
  attn_kernel<<<512, 256, 0, stream>>>(qbuf, kbuf, vT, pacc, pml);
  combine_spatial_kernel<<<4096, 256, 0, stream>>>(pacc, pml, locf, E, PH2e);
  gemm64_kernel<2, 384><<<dim3(128, 4), 256, 0, stream>>>(
      PH2e, LDE, W_big, bias_big, nullptr, nullptr, nullptr, nullptr, gxs);
  final_kernel<<<2048, 256, 0, stream>>>(gxs, ph, gamma, beta, out);
}